// Round 7
// baseline (588.927 us; speedup 1.0000x reference)
//
#include <hip/hip_runtime.h>
#include <stdint.h>

// ---------------------------------------------------------------------------
// Char segmentation loss — round 9.
// d_out: [0]=loss_low, [1]=loss_middle, [2..)=mask_low (512*27*1024 f32 0/1).
//
// R8 post-mortem: asm clobbers defeated the scheduler -> VGPR 176, occ 11%,
// 258 us. Ledger: every "all 27 channels per thread" variant pins VGPR ~100+
// (54 accum regs) or spills under caps. Best mains: R4 134 us, R2 140 us.
// R9: change the DECOMPOSITION. Phase A per thread (2 px): one-pass softmax
// stats with transient l[27], write m/inv/(bits<<1|fmw) to 5 KB LDS; CE
// butterfly+atomic per wave. Phase B: wave w owns channels [7w,7w+7) —
// per channel, 64 lanes sweep the 512 slice pixels (8 coalesced iters),
// prob recomputed (bit-identical, L2-hit re-read, R4-verified pattern),
// TWO accumulator regs, one butterfly per channel, lane0 atomicAdd.
// No caps, no clobbers. Summation regrouped only (absmax 0.0 held through
// all prior regroupings). s2-analytic prep kept.
// ---------------------------------------------------------------------------

static __device__ __forceinline__ float wave_reduce_add(float v) {
  v += __shfl_xor(v, 1, 64);
  v += __shfl_xor(v, 2, 64);
  v += __shfl_xor(v, 4, 64);
  v += __shfl_xor(v, 8, 64);
  v += __shfl_xor(v, 16, 64);
  v += __shfl_xor(v, 32, 64);
  return v;
}

// Thresholded attention bits for one output column (src coord), replicating
// jax.image.resize half-pixel bilinear (antialias=False); edge == clamp.
// Frozen from R1 (absmax was 0.0) — do not touch the rounding.
static __device__ __forceinline__ uint32_t attn_bits(const float* sattn, float src,
                                                     int lens, float alpha) {
  const int k0 = (int)floorf(src);
  uint32_t bits = 0u;
  if (k0 < 0 || k0 >= 31) {
    const int kk = (k0 < 0) ? 0 : 31;
    for (int c = 0; c < 26; ++c) {
      float v = (c < lens) ? sattn[c * 32 + kk] : 0.0f;
      if (v > alpha) bits |= (1u << c);
    }
  } else {
    const float frac = src - (float)k0;  // exact (multiples of 1/8)
    const float w1 = frac, w0 = 1.0f - frac;
    for (int c = 0; c < 26; ++c) {
      // __f*_rn: forbid fma contraction so we bit-match the reference dot.
      float v = __fadd_rn(__fmul_rn(w0, sattn[c * 32 + k0]),
                          __fmul_rn(w1, sattn[c * 32 + k0 + 1]));
      v = (c < lens) ? v : 0.0f;
      if (v > alpha) bits |= (1u << c);
    }
  }
  return bits;
}

// Prep: per-(b,x) attention bits for both widths; zero inter/s1 accumulators;
// compute s2[c] (mask pixel counts) analytically: for c>=1,
//   s2[c] = sum_x attn_bit(c,x) * colcount(x),  colcount(x) = sum_y fm(y,x)
// and s2[0] = HW - sum fm. Integer counts < 2^24 -> exact in f32, identical
// to per-pixel accumulation. Verified absmax 0.0 in R3..R8.
__global__ __launch_bounds__(192) void prep_kernel(
    const float* __restrict__ attn,   // [512,26,32]
    const float* __restrict__ fore,   // [512,4096]
    const int* __restrict__ length,   // [512]
    const float* __restrict__ alpha_p,
    uint32_t* __restrict__ bits_mid,  // [512,128]
    uint32_t* __restrict__ bits_low,  // [512,64]
    float* __restrict__ acc_mid,      // [512,81]
    float* __restrict__ acc_low,      // [512,81]
    float* __restrict__ ce) {         // [2]
  __shared__ float sattn[26 * 32];
  __shared__ int scnt_mid[128];
  __shared__ int scnt_low[64];
  __shared__ uint32_t sbits_mid[128];
  __shared__ uint32_t sbits_low[64];
  const int b = blockIdx.x;
  const int t = threadIdx.x;
  for (int i = t; i < 832; i += 192) sattn[i] = attn[b * 832 + i];
  if (t < 54) { acc_mid[b * 81 + t] = 0.0f; acc_low[b * 81 + t] = 0.0f; }
  if (b == 0 && t >= 96 && t < 98) ce[t - 96] = 0.0f;

  const float* fb = fore + (size_t)b * 4096;
  if (t < 128) {
    // mid fm column count: fm = fore >= 0.4
    int cnt = 0;
    for (int y = 0; y < 32; ++y) cnt += (fb[y * 128 + t] >= 0.4f) ? 1 : 0;
    scnt_mid[t] = cnt;
  } else {
    // low fm column count: exact 4-tap half-pixel average, frozen rounding.
    const int x = t - 128;
    int cnt = 0;
    for (int y = 0; y < 16; ++y) {
      const float2* fr = (const float2*)(fb + (size_t)(2 * y) * 128 + 2 * x);
      const float2 f0 = fr[0];
      const float2 f1 = fr[64];
      const float t0 = __fadd_rn(0.5f * f0.x, 0.5f * f1.x);
      const float t1 = __fadd_rn(0.5f * f0.y, 0.5f * f1.y);
      const float fmv = __fadd_rn(0.5f * t0, 0.5f * t1);
      cnt += (fmv >= 0.4f) ? 1 : 0;
    }
    scnt_low[x] = cnt;
  }
  __syncthreads();

  const float alpha = alpha_p[0];
  const int lens = length[b] - 1;
  if (t < 128) {
    const float src = 0.25f * (float)t - 0.375f;  // 128 -> 32
    const uint32_t bits = attn_bits(sattn, src, lens, alpha);
    bits_mid[b * 128 + t] = bits;
    sbits_mid[t] = bits;
  } else {
    const int x = t - 128;
    const float src = 0.5f * (float)x - 0.25f;    // 64 -> 32
    const uint32_t bits = attn_bits(sattn, src, lens, alpha);
    bits_low[b * 64 + x] = bits;
    sbits_low[x] = bits;
  }
  __syncthreads();

  if (t < 27) {
    const int c = t;
    int s2;
    if (c == 0) {
      int tot = 0;
      for (int x = 0; x < 128; ++x) tot += scnt_mid[x];
      s2 = 4096 - tot;
    } else {
      s2 = 0;
      for (int x = 0; x < 128; ++x)
        s2 += (int)((sbits_mid[x] >> (c - 1)) & 1u) * scnt_mid[x];
    }
    acc_mid[b * 81 + 54 + c] = (float)s2;
  } else if (t >= 64 && t < 91) {
    const int c = t - 64;
    int s2;
    if (c == 0) {
      int tot = 0;
      for (int x = 0; x < 64; ++x) tot += scnt_low[x];
      s2 = 1024 - tot;
    } else {
      s2 = 0;
      for (int x = 0; x < 64; ++x)
        s2 += (int)((sbits_low[x] >> (c - 1)) & 1u) * scnt_low[x];
    }
    acc_low[b * 81 + 54 + c] = (float)s2;
  }
}

// Main: blocks [0,4096) = mid slices (8 per b), [4096,5120) = low (2 per b).
// Phase A: per-thread softmax stats (2 pixels, transient l[27]) -> LDS.
// Phase B: channel-split across waves, 2 accumulator regs, coalesced sweeps.
__global__ __launch_bounds__(256) void main_kernel(
    const float* __restrict__ cf_mid,   // [512,27,4096]
    const float* __restrict__ cf_low,   // [512,27,1024]
    const float* __restrict__ fore,     // [512,4096]
    float* __restrict__ out,
    const uint32_t* __restrict__ bits_mid,
    const uint32_t* __restrict__ bits_low,
    float* __restrict__ acc_mid,
    float* __restrict__ acc_low,
    float* __restrict__ ce) {
  __shared__ float sm[512];     // per-slice-pixel max
  __shared__ float sinv[512];   // per-slice-pixel 1/sum_exp
  __shared__ uint32_t sw[512];  // (bits<<1) | fmw
  const int t = threadIdx.x;
  const int lane = t & 63;
  const int wave = t >> 6;
  const int bid = blockIdx.x;
  const bool low = (bid >= 4096);
  int b, p0, W, HW;
  const float* cf;
  const uint32_t* bitsp;
  float* acc;
  if (low) {
    const int idx = bid - 4096;
    b = idx >> 1; p0 = (idx & 1) << 9; W = 64; HW = 1024;
    cf = cf_low; bitsp = bits_low + (size_t)b * 64; acc = acc_low;
  } else {
    b = bid >> 3; p0 = (bid & 7) << 9; W = 128; HW = 4096;
    cf = cf_mid; bitsp = bits_mid + (size_t)b * 128; acc = acc_mid;
  }
  const float* cfb = cf + (size_t)b * 27 * HW;
  const float* fb = fore + (size_t)b * 4096;
  float* mout = out + 2 + (size_t)b * 27 * 1024;  // low only

  float cesum = 0.0f;

  // ---- Phase A: per-pixel softmax stats (R2 pass1+2, transient l[27]) ----
#pragma unroll
  for (int k = 0; k < 2; ++k) {
    const int pp = t + (k << 8);   // slice-local pixel
    const int p = p0 + pp;
    const int x = p & (W - 1);

    int fmw;
    if (low) {
      // fm_low: exact 4-tap half-pixel average, frozen from R1.
      const int y = p >> 6;
      const float2* fr = (const float2*)(fb + (size_t)(2 * y) * 128 + 2 * x);
      const float2 f0 = fr[0];
      const float2 f1 = fr[64];
      const float t0 = __fadd_rn(0.5f * f0.x, 0.5f * f1.x);
      const float t1 = __fadd_rn(0.5f * f0.y, 0.5f * f1.y);
      const float fmv = __fadd_rn(0.5f * t0, 0.5f * t1);
      fmw = (fmv >= 0.4f) ? 1 : 0;
    } else {
      fmw = (fb[p] >= 0.4f) ? 1 : 0;
    }

    const uint32_t bits = bitsp[x];
    const int target = fmw ? (int)__ffs(bits) : 0;
    const float* cp = cfb + p;

    float l[27];  // transient: dead after this k-iteration
    float m = -1e30f, lt = 0.0f;
#pragma unroll
    for (int c = 0; c < 27; ++c) {
      const float v = cp[(size_t)c * HW];
      l[c] = v;
      m = fmaxf(m, v);
      lt = (c == target) ? v : lt;
    }
    float s = 0.0f;
#pragma unroll
    for (int c = 0; c < 27; ++c) s += __expf(l[c] - m);
    const float inv = 1.0f / s;
    cesum += (m + __logf(s) - lt);  // -log p(target)

    sm[pp] = m;
    sinv[pp] = inv;
    sw[pp] = (bits << 1) | (uint32_t)fmw;

    // mask_low writes (bits/fmw only)
    if (low) {
#pragma unroll
      for (int c = 0; c < 27; ++c) {
        float mf;
        if (c == 0) mf = (float)(1 - fmw);
        else mf = (float)(((bits >> (c - 1)) & 1u) & (uint32_t)fmw);
        mout[(size_t)c * 1024 + p] = mf;
      }
    }
  }

  // CE partial: butterfly per wave, one atomic per wave.
  cesum = wave_reduce_add(cesum);
  if (lane == 0) atomicAdd(&ce[low ? 0 : 1], cesum);

  __syncthreads();

  // ---- Phase B: wave w owns channels [7w, min(7w+7,27)); 2 accum regs ----
  const int cbeg = wave * 7;
  const int cend = (wave == 3) ? 27 : (cbeg + 7);
  for (int c = cbeg; c < cend; ++c) {
    const float* cpc = cfb + (size_t)c * HW + p0;
    float aS = 0.0f, aI = 0.0f;
#pragma unroll
    for (int it = 0; it < 8; ++it) {
      const int pp = (it << 6) + lane;
      const float v = cpc[pp];
      const float prob = __expf(v - sm[pp]) * sinv[pp];  // bit-identical
      const uint32_t w = sw[pp];
      float mf;
      if (c == 0) mf = (float)(1u - (w & 1u));
      else mf = (float)(((w >> c) & 1u) & (w & 1u));
      aS += prob;
      aI += prob * mf;
    }
    aI = wave_reduce_add(aI);
    aS = wave_reduce_add(aS);
    if (lane == 0) {
      atomicAdd(&acc[(size_t)b * 81 + c], aI);
      atomicAdd(&acc[(size_t)b * 81 + 27 + c], aS);
    }
  }
}

// Final: block 0 -> loss_low (out[0]), block 1 -> loss_middle (out[1]).
__global__ __launch_bounds__(256) void final_kernel(
    const float* __restrict__ acc_mid,
    const float* __restrict__ acc_low,
    const float* __restrict__ ce,
    const int* __restrict__ length,
    float* __restrict__ out) {
  const int B = blockIdx.x;  // 0=low, 1=mid
  const float* acc = (B == 0) ? acc_low : acc_mid;
  const float hw = (B == 0) ? 1024.0f : 4096.0f;
  const int t = threadIdx.x;
  float dsum = 0.0f;
  for (int b = t; b < 512; b += 256) {
    const int lens = length[b] - 1;
    const float* a = acc + (size_t)b * 81;
    float d = 0.0f;
    for (int c = 1; c < 27; ++c) {
      const float I = a[c], S1 = a[27 + c], S2 = a[54 + c];
      const float score = (2.0f * I + 1.0f) / (S1 + S2 + 1.0f);
      if (c <= lens) d += (1.0f - score);
    }
    dsum += d / (float)lens;
  }
  __shared__ float red[4];
  const int wave = t >> 6, lane = t & 63;
  dsum = wave_reduce_add(dsum);
  if (lane == 0) red[wave] = dsum;
  __syncthreads();
  if (t == 0) {
    const float dice = red[0] + red[1] + red[2] + red[3];
    out[B] = dice * (1.0f / 512.0f) + ce[B] * (1.0f / (512.0f * hw));
  }
}

extern "C" void kernel_launch(void* const* d_in, const int* in_sizes, int n_in,
                              void* d_out, int out_size, void* d_ws, size_t ws_size,
                              hipStream_t stream) {
  const float* cf_mid = (const float*)d_in[0];  // [512,27,32,128]
  const float* cf_low = (const float*)d_in[1];  // [512,27,16,64]
  const float* attn   = (const float*)d_in[2];  // [512,26,32]
  const float* fore   = (const float*)d_in[3];  // [512,1,32,128]
  const int*   length = (const int*)d_in[4];    // [512]
  const float* alpha  = (const float*)d_in[5];  // scalar
  float* out = (float*)d_out;

  // ws layout
  uint32_t* bits_mid = (uint32_t*)d_ws;                   // 512*128
  uint32_t* bits_low = bits_mid + 512 * 128;              // 512*64
  float* acc_mid = (float*)(bits_low + 512 * 64);         // 512*81
  float* acc_low = acc_mid + 512 * 81;                    // 512*81
  float* ce = acc_low + 512 * 81;                         // 2

  hipLaunchKernelGGL(prep_kernel, dim3(512), dim3(192), 0, stream,
                     attn, fore, length, alpha, bits_mid, bits_low,
                     acc_mid, acc_low, ce);
  hipLaunchKernelGGL(main_kernel, dim3(5120), dim3(256), 0, stream,
                     cf_mid, cf_low, fore, out, bits_mid, bits_low,
                     acc_mid, acc_low, ce);
  hipLaunchKernelGGL(final_kernel, dim3(2), dim3(256), 0, stream,
                     acc_mid, acc_low, ce, length, out);
}

// Round 8
// 452.338 us; speedup vs baseline: 1.3020x; 1.3020x over previous
//
#include <hip/hip_runtime.h>
#include <stdint.h>

// ---------------------------------------------------------------------------
// Char segmentation loss — round 10.
// d_out: [0]=loss_low, [1]=loss_middle, [2..)=mask_low (512*27*1024 f32 0/1).
//
// R9 post-mortem: VGPR 56 / occ 35% but 303 us — Phase B duplicated the whole
// load+exp sweep (FETCH 148->265 MB) behind LDS+barrier. R8: 176 VGPR -> 258.
// Requirements now precise: ONE sweep per pixel, NO accumulator arrays, no
// LDS/barrier in the pixel path, no caps/clobbers.
// R10: 1 pixel/thread. prob[27] IS the per-thread contribution (no
// inter[]/s1[] arrays -> live set ~l[27]+misc). Block epilogue: prob -> LDS
// transpose [27][264] (conflict-free), one sync, wave w sums channels
// {w,w+4,...} over 256 px (4 coalesced LDS reads/lane + butterfly), lane0
// atomicAdd. LDS 29.5 KB -> 5 blocks/CU = 20 waves/CU, robust for any
// VGPR <= 102. Same per-pixel math as R2 (27 loads, 27 exps); grid 10240.
// Only summation grouping changes (absmax 0.0 held through R1..R9).
// ---------------------------------------------------------------------------

static __device__ __forceinline__ float wave_reduce_add(float v) {
  v += __shfl_xor(v, 1, 64);
  v += __shfl_xor(v, 2, 64);
  v += __shfl_xor(v, 4, 64);
  v += __shfl_xor(v, 8, 64);
  v += __shfl_xor(v, 16, 64);
  v += __shfl_xor(v, 32, 64);
  return v;
}

// Thresholded attention bits for one output column (src coord), replicating
// jax.image.resize half-pixel bilinear (antialias=False); edge == clamp.
// Frozen from R1 (absmax was 0.0) — do not touch the rounding.
static __device__ __forceinline__ uint32_t attn_bits(const float* sattn, float src,
                                                     int lens, float alpha) {
  const int k0 = (int)floorf(src);
  uint32_t bits = 0u;
  if (k0 < 0 || k0 >= 31) {
    const int kk = (k0 < 0) ? 0 : 31;
    for (int c = 0; c < 26; ++c) {
      float v = (c < lens) ? sattn[c * 32 + kk] : 0.0f;
      if (v > alpha) bits |= (1u << c);
    }
  } else {
    const float frac = src - (float)k0;  // exact (multiples of 1/8)
    const float w1 = frac, w0 = 1.0f - frac;
    for (int c = 0; c < 26; ++c) {
      // __f*_rn: forbid fma contraction so we bit-match the reference dot.
      float v = __fadd_rn(__fmul_rn(w0, sattn[c * 32 + k0]),
                          __fmul_rn(w1, sattn[c * 32 + k0 + 1]));
      v = (c < lens) ? v : 0.0f;
      if (v > alpha) bits |= (1u << c);
    }
  }
  return bits;
}

// Prep: per-(b,x) attention bits for both widths; zero inter/s1 accumulators;
// compute s2[c] (mask pixel counts) analytically: for c>=1,
//   s2[c] = sum_x attn_bit(c,x) * colcount(x),  colcount(x) = sum_y fm(y,x)
// and s2[0] = HW - sum fm. Integer counts < 2^24 -> exact in f32, identical
// to per-pixel accumulation. Verified absmax 0.0 in R3..R9.
__global__ __launch_bounds__(192) void prep_kernel(
    const float* __restrict__ attn,   // [512,26,32]
    const float* __restrict__ fore,   // [512,4096]
    const int* __restrict__ length,   // [512]
    const float* __restrict__ alpha_p,
    uint32_t* __restrict__ bits_mid,  // [512,128]
    uint32_t* __restrict__ bits_low,  // [512,64]
    float* __restrict__ acc_mid,      // [512,81]
    float* __restrict__ acc_low,      // [512,81]
    float* __restrict__ ce) {         // [2]
  __shared__ float sattn[26 * 32];
  __shared__ int scnt_mid[128];
  __shared__ int scnt_low[64];
  __shared__ uint32_t sbits_mid[128];
  __shared__ uint32_t sbits_low[64];
  const int b = blockIdx.x;
  const int t = threadIdx.x;
  for (int i = t; i < 832; i += 192) sattn[i] = attn[b * 832 + i];
  if (t < 54) { acc_mid[b * 81 + t] = 0.0f; acc_low[b * 81 + t] = 0.0f; }
  if (b == 0 && t >= 96 && t < 98) ce[t - 96] = 0.0f;

  const float* fb = fore + (size_t)b * 4096;
  if (t < 128) {
    // mid fm column count: fm = fore >= 0.4
    int cnt = 0;
    for (int y = 0; y < 32; ++y) cnt += (fb[y * 128 + t] >= 0.4f) ? 1 : 0;
    scnt_mid[t] = cnt;
  } else {
    // low fm column count: exact 4-tap half-pixel average, frozen rounding.
    const int x = t - 128;
    int cnt = 0;
    for (int y = 0; y < 16; ++y) {
      const float2* fr = (const float2*)(fb + (size_t)(2 * y) * 128 + 2 * x);
      const float2 f0 = fr[0];
      const float2 f1 = fr[64];
      const float t0 = __fadd_rn(0.5f * f0.x, 0.5f * f1.x);
      const float t1 = __fadd_rn(0.5f * f0.y, 0.5f * f1.y);
      const float fmv = __fadd_rn(0.5f * t0, 0.5f * t1);
      cnt += (fmv >= 0.4f) ? 1 : 0;
    }
    scnt_low[x] = cnt;
  }
  __syncthreads();

  const float alpha = alpha_p[0];
  const int lens = length[b] - 1;
  if (t < 128) {
    const float src = 0.25f * (float)t - 0.375f;  // 128 -> 32
    const uint32_t bits = attn_bits(sattn, src, lens, alpha);
    bits_mid[b * 128 + t] = bits;
    sbits_mid[t] = bits;
  } else {
    const int x = t - 128;
    const float src = 0.5f * (float)x - 0.25f;    // 64 -> 32
    const uint32_t bits = attn_bits(sattn, src, lens, alpha);
    bits_low[b * 64 + x] = bits;
    sbits_low[x] = bits;
  }
  __syncthreads();

  if (t < 27) {
    const int c = t;
    int s2;
    if (c == 0) {
      int tot = 0;
      for (int x = 0; x < 128; ++x) tot += scnt_mid[x];
      s2 = 4096 - tot;
    } else {
      s2 = 0;
      for (int x = 0; x < 128; ++x)
        s2 += (int)((sbits_mid[x] >> (c - 1)) & 1u) * scnt_mid[x];
    }
    acc_mid[b * 81 + 54 + c] = (float)s2;
  } else if (t >= 64 && t < 91) {
    const int c = t - 64;
    int s2;
    if (c == 0) {
      int tot = 0;
      for (int x = 0; x < 64; ++x) tot += scnt_low[x];
      s2 = 1024 - tot;
    } else {
      s2 = 0;
      for (int x = 0; x < 64; ++x)
        s2 += (int)((sbits_low[x] >> (c - 1)) & 1u) * scnt_low[x];
    }
    acc_low[b * 81 + 54 + c] = (float)s2;
  }
}

// Main: 1 pixel per thread, 256 px per block.
// blocks [0,8192): mid, b = bid>>4, p0 = (bid&15)<<8
// blocks [8192,10240): low, idx = bid-8192, b = idx>>2, p0 = (idx&3)<<8
__global__ __launch_bounds__(256) void main_kernel(
    const float* __restrict__ cf_mid,   // [512,27,4096]
    const float* __restrict__ cf_low,   // [512,27,1024]
    const float* __restrict__ fore,     // [512,4096]
    float* __restrict__ out,
    const uint32_t* __restrict__ bits_mid,
    const uint32_t* __restrict__ bits_low,
    float* __restrict__ acc_mid,
    float* __restrict__ acc_low,
    float* __restrict__ ce) {
  __shared__ float sP[27 * 264];   // 28512 B, stride 264 -> conflict-free
  __shared__ uint32_t smw[256];    // per-pixel mask word
  __shared__ float redce[4];
  const int t = threadIdx.x;
  const int lane = t & 63;
  const int wave = t >> 6;
  const int bid = blockIdx.x;
  const bool low = (bid >= 8192);
  int b, p0, W, HW;
  const float* cf;
  const uint32_t* bitsp;
  float* acc;
  if (low) {
    const int idx = bid - 8192;
    b = idx >> 2; p0 = (idx & 3) << 8; W = 64; HW = 1024;
    cf = cf_low; bitsp = bits_low + (size_t)b * 64; acc = acc_low;
  } else {
    b = bid >> 4; p0 = (bid & 15) << 8; W = 128; HW = 4096;
    cf = cf_mid; bitsp = bits_mid + (size_t)b * 128; acc = acc_mid;
  }
  const float* cfb = cf + (size_t)b * 27 * HW;
  const float* fb = fore + (size_t)b * 4096;
  float* mout = out + 2 + (size_t)b * 27 * 1024;  // low only

  const int p = p0 + t;         // this thread's pixel
  const int x = p & (W - 1);

  int fmw;
  if (low) {
    // fm_low: exact 4-tap half-pixel average, frozen from R1.
    const int y = p >> 6;
    const float2* fr = (const float2*)(fb + (size_t)(2 * y) * 128 + 2 * x);
    const float2 f0 = fr[0];
    const float2 f1 = fr[64];
    const float t0 = __fadd_rn(0.5f * f0.x, 0.5f * f1.x);
    const float t1 = __fadd_rn(0.5f * f0.y, 0.5f * f1.y);
    const float fmv = __fadd_rn(0.5f * t0, 0.5f * t1);
    fmw = (fmv >= 0.4f) ? 1 : 0;
  } else {
    fmw = (fb[p] >= 0.4f) ? 1 : 0;
  }

  const uint32_t bits = bitsp[x];
  const int target = fmw ? (int)__ffs(bits) : 0;
  const float* cp = cfb + p;

  // Single sweep: 27 loads -> regs, max + target logit (R2's exact fold).
  float l[27];
  float m = -1e30f, lt = 0.0f;
#pragma unroll
  for (int c = 0; c < 27; ++c) {
    const float v = cp[(size_t)c * HW];
    l[c] = v;
    m = fmaxf(m, v);
    lt = (c == target) ? v : lt;
  }
  float s = 0.0f;
#pragma unroll
  for (int c = 0; c < 27; ++c) {
    const float e = __expf(l[c] - m);
    l[c] = e;
    s += e;
  }
  const float inv = 1.0f / s;
  float cesum = (m + __logf(s) - lt);  // -log p(target)

  // mask word: bit c == mask channel c for this pixel.
  const uint32_t mw = fmw ? (bits << 1) : 1u;
  smw[t] = mw;

  // prob -> LDS transpose; mask_low store (low only).
#pragma unroll
  for (int c = 0; c < 27; ++c) {
    const float prob = l[c] * inv;
    sP[c * 264 + t] = prob;
    if (low) mout[(size_t)c * 1024 + p] = (float)((mw >> c) & 1u);
  }

  // CE partial.
  cesum = wave_reduce_add(cesum);
  if (lane == 0) redce[wave] = cesum;
  __syncthreads();
  if (t == 0)
    atomicAdd(&ce[low ? 0 : 1], redce[0] + redce[1] + redce[2] + redce[3]);

  // Epilogue: wave w reduces channels {w, w+4, ...} over the 256 pixels.
  uint32_t mw4[4];
#pragma unroll
  for (int q = 0; q < 4; ++q) mw4[q] = smw[(q << 6) + lane];

  for (int c = wave; c < 27; c += 4) {
    float vS = 0.0f, vI = 0.0f;
#pragma unroll
    for (int q = 0; q < 4; ++q) {
      const float v = sP[c * 264 + (q << 6) + lane];
      vS += v;
      vI += ((mw4[q] >> c) & 1u) ? v : 0.0f;
    }
    vS = wave_reduce_add(vS);
    vI = wave_reduce_add(vI);
    if (lane == 0) {
      atomicAdd(&acc[(size_t)b * 81 + c], vI);
      atomicAdd(&acc[(size_t)b * 81 + 27 + c], vS);
    }
  }
}

// Final: block 0 -> loss_low (out[0]), block 1 -> loss_middle (out[1]).
__global__ __launch_bounds__(256) void final_kernel(
    const float* __restrict__ acc_mid,
    const float* __restrict__ acc_low,
    const float* __restrict__ ce,
    const int* __restrict__ length,
    float* __restrict__ out) {
  const int B = blockIdx.x;  // 0=low, 1=mid
  const float* acc = (B == 0) ? acc_low : acc_mid;
  const float hw = (B == 0) ? 1024.0f : 4096.0f;
  const int t = threadIdx.x;
  float dsum = 0.0f;
  for (int b = t; b < 512; b += 256) {
    const int lens = length[b] - 1;
    const float* a = acc + (size_t)b * 81;
    float d = 0.0f;
    for (int c = 1; c < 27; ++c) {
      const float I = a[c], S1 = a[27 + c], S2 = a[54 + c];
      const float score = (2.0f * I + 1.0f) / (S1 + S2 + 1.0f);
      if (c <= lens) d += (1.0f - score);
    }
    dsum += d / (float)lens;
  }
  __shared__ float red[4];
  const int wave = t >> 6, lane = t & 63;
  dsum = wave_reduce_add(dsum);
  if (lane == 0) red[wave] = dsum;
  __syncthreads();
  if (t == 0) {
    const float dice = red[0] + red[1] + red[2] + red[3];
    out[B] = dice * (1.0f / 512.0f) + ce[B] * (1.0f / (512.0f * hw));
  }
}

extern "C" void kernel_launch(void* const* d_in, const int* in_sizes, int n_in,
                              void* d_out, int out_size, void* d_ws, size_t ws_size,
                              hipStream_t stream) {
  const float* cf_mid = (const float*)d_in[0];  // [512,27,32,128]
  const float* cf_low = (const float*)d_in[1];  // [512,27,16,64]
  const float* attn   = (const float*)d_in[2];  // [512,26,32]
  const float* fore   = (const float*)d_in[3];  // [512,1,32,128]
  const int*   length = (const int*)d_in[4];    // [512]
  const float* alpha  = (const float*)d_in[5];  // scalar
  float* out = (float*)d_out;

  // ws layout
  uint32_t* bits_mid = (uint32_t*)d_ws;                   // 512*128
  uint32_t* bits_low = bits_mid + 512 * 128;              // 512*64
  float* acc_mid = (float*)(bits_low + 512 * 64);         // 512*81
  float* acc_low = acc_mid + 512 * 81;                    // 512*81
  float* ce = acc_low + 512 * 81;                         // 2

  hipLaunchKernelGGL(prep_kernel, dim3(512), dim3(192), 0, stream,
                     attn, fore, length, alpha, bits_mid, bits_low,
                     acc_mid, acc_low, ce);
  hipLaunchKernelGGL(main_kernel, dim3(10240), dim3(256), 0, stream,
                     cf_mid, cf_low, fore, out, bits_mid, bits_low,
                     acc_mid, acc_low, ce);
  hipLaunchKernelGGL(final_kernel, dim3(2), dim3(256), 0, stream,
                     acc_mid, acc_low, ce, length, out);
}

// Round 9
// 392.185 us; speedup vs baseline: 1.5017x; 1.1534x over previous
//
#include <hip/hip_runtime.h>
#include <stdint.h>

// ---------------------------------------------------------------------------
// Char segmentation loss — round 11.
// d_out: [0]=loss_low, [1]=loss_middle, [2..)=mask_low (512*27*1024 f32 0/1).
//
// R10 post-mortem: occupancy 42% did NOT help (171 us) -> occupancy theory
// dead. Hidden limiter: the LDS pipe. __shfl_xor = ds_swizzle/bpermute on the
// single per-CU LDS unit; R2's 54-value butterfly epilogue ~= 1320 LDS ops
// per block ~= 55 us chip-wide; R10's LDS transpose added ~50 more.
// R11: base = R2 main (single sweep, l[27] cache, 54 reg accums, no caps/
// clobbers, VGPR ~104) + R3's s2-analytic prep. ONLY change: butterflies ->
// DPP reduction (v_add_f32 + update_dpp: quad_perm/half_mirror/mirror/
// bcast15/bcast31) = 6 VALU adds, zero LDS-pipe traffic; total in lane 63.
// Summation regrouping only — the same class of change that held absmax 0.0
// through R1..R10 (slice splits, atomic reordering, chunked groups).
// ---------------------------------------------------------------------------

// DPP wave64 sum: after the 6 steps lanes 48-63 hold the full sum.
#define DPP_ADD(v, ctrl)                                                      \
  v += __int_as_float(__builtin_amdgcn_update_dpp(                            \
      0, __float_as_int(v), (ctrl), 0xf, 0xf, true))

static __device__ __forceinline__ float dpp_reduce_add(float v) {
  DPP_ADD(v, 0xB1);   // quad_perm [1,0,3,2]  -> pair sums
  DPP_ADD(v, 0x4E);   // quad_perm [2,3,0,1]  -> quad sums
  DPP_ADD(v, 0x141);  // row_half_mirror      -> 8-sums
  DPP_ADD(v, 0x140);  // row_mirror           -> 16-sums (per row)
  DPP_ADD(v, 0x142);  // row_bcast:15         -> rows 1,3 = pair-of-rows sums
  DPP_ADD(v, 0x143);  // row_bcast:31         -> lanes 48-63 = full sum
  return v;           // valid in lane 63
}

static __device__ __forceinline__ float wave_reduce_add(float v) {
  v += __shfl_xor(v, 1, 64);
  v += __shfl_xor(v, 2, 64);
  v += __shfl_xor(v, 4, 64);
  v += __shfl_xor(v, 8, 64);
  v += __shfl_xor(v, 16, 64);
  v += __shfl_xor(v, 32, 64);
  return v;
}

// Thresholded attention bits for one output column (src coord), replicating
// jax.image.resize half-pixel bilinear (antialias=False); edge == clamp.
// Frozen from R1 (absmax was 0.0) — do not touch the rounding.
static __device__ __forceinline__ uint32_t attn_bits(const float* sattn, float src,
                                                     int lens, float alpha) {
  const int k0 = (int)floorf(src);
  uint32_t bits = 0u;
  if (k0 < 0 || k0 >= 31) {
    const int kk = (k0 < 0) ? 0 : 31;
    for (int c = 0; c < 26; ++c) {
      float v = (c < lens) ? sattn[c * 32 + kk] : 0.0f;
      if (v > alpha) bits |= (1u << c);
    }
  } else {
    const float frac = src - (float)k0;  // exact (multiples of 1/8)
    const float w1 = frac, w0 = 1.0f - frac;
    for (int c = 0; c < 26; ++c) {
      // __f*_rn: forbid fma contraction so we bit-match the reference dot.
      float v = __fadd_rn(__fmul_rn(w0, sattn[c * 32 + k0]),
                          __fmul_rn(w1, sattn[c * 32 + k0 + 1]));
      v = (c < lens) ? v : 0.0f;
      if (v > alpha) bits |= (1u << c);
    }
  }
  return bits;
}

// Prep: per-(b,x) attention bits for both widths; zero inter/s1 accumulators;
// compute s2[c] (mask pixel counts) analytically: for c>=1,
//   s2[c] = sum_x attn_bit(c,x) * colcount(x),  colcount(x) = sum_y fm(y,x)
// and s2[0] = HW - sum fm. Integer counts < 2^24 -> exact in f32, identical
// to per-pixel accumulation. Verified absmax 0.0 in R3..R10.
__global__ __launch_bounds__(192) void prep_kernel(
    const float* __restrict__ attn,   // [512,26,32]
    const float* __restrict__ fore,   // [512,4096]
    const int* __restrict__ length,   // [512]
    const float* __restrict__ alpha_p,
    uint32_t* __restrict__ bits_mid,  // [512,128]
    uint32_t* __restrict__ bits_low,  // [512,64]
    float* __restrict__ acc_mid,      // [512,81]
    float* __restrict__ acc_low,      // [512,81]
    float* __restrict__ ce) {         // [2]
  __shared__ float sattn[26 * 32];
  __shared__ int scnt_mid[128];
  __shared__ int scnt_low[64];
  __shared__ uint32_t sbits_mid[128];
  __shared__ uint32_t sbits_low[64];
  const int b = blockIdx.x;
  const int t = threadIdx.x;
  for (int i = t; i < 832; i += 192) sattn[i] = attn[b * 832 + i];
  if (t < 54) { acc_mid[b * 81 + t] = 0.0f; acc_low[b * 81 + t] = 0.0f; }
  if (b == 0 && t >= 96 && t < 98) ce[t - 96] = 0.0f;

  const float* fb = fore + (size_t)b * 4096;
  if (t < 128) {
    // mid fm column count: fm = fore >= 0.4
    int cnt = 0;
    for (int y = 0; y < 32; ++y) cnt += (fb[y * 128 + t] >= 0.4f) ? 1 : 0;
    scnt_mid[t] = cnt;
  } else {
    // low fm column count: exact 4-tap half-pixel average, frozen rounding.
    const int x = t - 128;
    int cnt = 0;
    for (int y = 0; y < 16; ++y) {
      const float2* fr = (const float2*)(fb + (size_t)(2 * y) * 128 + 2 * x);
      const float2 f0 = fr[0];
      const float2 f1 = fr[64];
      const float t0 = __fadd_rn(0.5f * f0.x, 0.5f * f1.x);
      const float t1 = __fadd_rn(0.5f * f0.y, 0.5f * f1.y);
      const float fmv = __fadd_rn(0.5f * t0, 0.5f * t1);
      cnt += (fmv >= 0.4f) ? 1 : 0;
    }
    scnt_low[x] = cnt;
  }
  __syncthreads();

  const float alpha = alpha_p[0];
  const int lens = length[b] - 1;
  if (t < 128) {
    const float src = 0.25f * (float)t - 0.375f;  // 128 -> 32
    const uint32_t bits = attn_bits(sattn, src, lens, alpha);
    bits_mid[b * 128 + t] = bits;
    sbits_mid[t] = bits;
  } else {
    const int x = t - 128;
    const float src = 0.5f * (float)x - 0.25f;    // 64 -> 32
    const uint32_t bits = attn_bits(sattn, src, lens, alpha);
    bits_low[b * 64 + x] = bits;
    sbits_low[x] = bits;
  }
  __syncthreads();

  if (t < 27) {
    const int c = t;
    int s2;
    if (c == 0) {
      int tot = 0;
      for (int x = 0; x < 128; ++x) tot += scnt_mid[x];
      s2 = 4096 - tot;
    } else {
      s2 = 0;
      for (int x = 0; x < 128; ++x)
        s2 += (int)((sbits_mid[x] >> (c - 1)) & 1u) * scnt_mid[x];
    }
    acc_mid[b * 81 + 54 + c] = (float)s2;
  } else if (t >= 64 && t < 91) {
    const int c = t - 64;
    int s2;
    if (c == 0) {
      int tot = 0;
      for (int x = 0; x < 64; ++x) tot += scnt_low[x];
      s2 = 1024 - tot;
    } else {
      s2 = 0;
      for (int x = 0; x < 64; ++x)
        s2 += (int)((sbits_low[x] >> (c - 1)) & 1u) * scnt_low[x];
    }
    acc_low[b * 81 + 54 + c] = (float)s2;
  }
}

// Main: blocks [0,4096) = mid slices (8 per b), [4096,5120) = low (2 per b).
// R2's single-sweep main loop (l[27] cache, 54 reg accumulators); epilogue
// reduction via DPP (VALU pipe) instead of shfl (LDS pipe).
__global__ __launch_bounds__(256) void main_kernel(
    const float* __restrict__ cf_mid,   // [512,27,4096]
    const float* __restrict__ cf_low,   // [512,27,1024]
    const float* __restrict__ fore,     // [512,4096]
    float* __restrict__ out,
    const uint32_t* __restrict__ bits_mid,
    const uint32_t* __restrict__ bits_low,
    float* __restrict__ acc_mid,
    float* __restrict__ acc_low,
    float* __restrict__ ce) {
  const int t = threadIdx.x;
  const int bid = blockIdx.x;
  const bool low = (bid >= 4096);
  int b, p0, W, HW;
  const float* cf;
  const uint32_t* bitsp;
  float* acc;
  if (low) {
    const int idx = bid - 4096;
    b = idx >> 1; p0 = (idx & 1) << 9; W = 64; HW = 1024;
    cf = cf_low; bitsp = bits_low + (size_t)b * 64; acc = acc_low;
  } else {
    b = bid >> 3; p0 = (bid & 7) << 9; W = 128; HW = 4096;
    cf = cf_mid; bitsp = bits_mid + (size_t)b * 128; acc = acc_mid;
  }
  const float* cfb = cf + (size_t)b * 27 * HW;
  const float* fb = fore + (size_t)b * 4096;
  float* mout = out + 2 + (size_t)b * 27 * 1024;  // low only

  float inter[27], s1[27];
#pragma unroll
  for (int c = 0; c < 27; ++c) { inter[c] = 0.0f; s1[c] = 0.0f; }
  float cesum = 0.0f;

  for (int k = 0; k < 2; ++k) {
    const int p = p0 + t + (k << 8);
    const int x = p & (W - 1);

    int fmw;
    if (low) {
      // fm_low: exact 4-tap half-pixel average, frozen from R1.
      const int y = p >> 6;
      const float2* fr = (const float2*)(fb + (size_t)(2 * y) * 128 + 2 * x);
      const float2 f0 = fr[0];
      const float2 f1 = fr[64];
      const float t0 = __fadd_rn(0.5f * f0.x, 0.5f * f1.x);
      const float t1 = __fadd_rn(0.5f * f0.y, 0.5f * f1.y);
      const float fmv = __fadd_rn(0.5f * t0, 0.5f * t1);
      fmw = (fmv >= 0.4f) ? 1 : 0;
    } else {
      fmw = (fb[p] >= 0.4f) ? 1 : 0;
    }

    const uint32_t bits = bitsp[x];
    const int target = fmw ? (int)__ffs(bits) : 0;

    float l[27];
    float m = -1e30f, lt = 0.0f;
#pragma unroll
    for (int c = 0; c < 27; ++c) {
      const float v = cfb[(size_t)c * HW + p];
      l[c] = v;
      m = fmaxf(m, v);
      lt = (c == target) ? v : lt;
    }
    float s = 0.0f;
#pragma unroll
    for (int c = 0; c < 27; ++c) {
      const float e = __expf(l[c] - m);
      l[c] = e;
      s += e;
    }
    const float inv = 1.0f / s;
    cesum += (m + __logf(s) - lt);  // -log p(target)

#pragma unroll
    for (int c = 0; c < 27; ++c) {
      const float prob = l[c] * inv;
      s1[c] += prob;
      float mf;
      if (c == 0) mf = (float)(1 - fmw);
      else mf = (float)(((bits >> (c - 1)) & 1u) & (uint32_t)fmw);
      inter[c] += prob * mf;
      if (low) mout[(size_t)c * 1024 + p] = mf;
    }
  }

  // DPP reduce (VALU pipe; zero LDS-pipe traffic) + cross-wave LDS + atomics.
  __shared__ float red[4][55];
  const int wave = t >> 6, lane = t & 63;
#pragma unroll
  for (int c = 0; c < 27; ++c) {
    inter[c] = dpp_reduce_add(inter[c]);
    s1[c] = dpp_reduce_add(s1[c]);
  }
  cesum = dpp_reduce_add(cesum);
  if (lane == 63) {  // DPP total is valid in lane 63
#pragma unroll
    for (int c = 0; c < 27; ++c) {
      red[wave][c] = inter[c];
      red[wave][27 + c] = s1[c];
    }
    red[wave][54] = cesum;
  }
  __syncthreads();
  if (t < 55) {
    const float v = red[0][t] + red[1][t] + red[2][t] + red[3][t];
    if (t == 54) atomicAdd(&ce[low ? 0 : 1], v);
    else atomicAdd(&acc[(size_t)b * 81 + t], v);
  }
}

// Final: block 0 -> loss_low (out[0]), block 1 -> loss_middle (out[1]).
__global__ __launch_bounds__(256) void final_kernel(
    const float* __restrict__ acc_mid,
    const float* __restrict__ acc_low,
    const float* __restrict__ ce,
    const int* __restrict__ length,
    float* __restrict__ out) {
  const int B = blockIdx.x;  // 0=low, 1=mid
  const float* acc = (B == 0) ? acc_low : acc_mid;
  const float hw = (B == 0) ? 1024.0f : 4096.0f;
  const int t = threadIdx.x;
  float dsum = 0.0f;
  for (int b = t; b < 512; b += 256) {
    const int lens = length[b] - 1;
    const float* a = acc + (size_t)b * 81;
    float d = 0.0f;
    for (int c = 1; c < 27; ++c) {
      const float I = a[c], S1 = a[27 + c], S2 = a[54 + c];
      const float score = (2.0f * I + 1.0f) / (S1 + S2 + 1.0f);
      if (c <= lens) d += (1.0f - score);
    }
    dsum += d / (float)lens;
  }
  __shared__ float red[4];
  const int wave = t >> 6, lane = t & 63;
  dsum = wave_reduce_add(dsum);
  if (lane == 0) red[wave] = dsum;
  __syncthreads();
  if (t == 0) {
    const float dice = red[0] + red[1] + red[2] + red[3];
    out[B] = dice * (1.0f / 512.0f) + ce[B] * (1.0f / (512.0f * hw));
  }
}

extern "C" void kernel_launch(void* const* d_in, const int* in_sizes, int n_in,
                              void* d_out, int out_size, void* d_ws, size_t ws_size,
                              hipStream_t stream) {
  const float* cf_mid = (const float*)d_in[0];  // [512,27,32,128]
  const float* cf_low = (const float*)d_in[1];  // [512,27,16,64]
  const float* attn   = (const float*)d_in[2];  // [512,26,32]
  const float* fore   = (const float*)d_in[3];  // [512,1,32,128]
  const int*   length = (const int*)d_in[4];    // [512]
  const float* alpha  = (const float*)d_in[5];  // scalar
  float* out = (float*)d_out;

  // ws layout
  uint32_t* bits_mid = (uint32_t*)d_ws;                   // 512*128
  uint32_t* bits_low = bits_mid + 512 * 128;              // 512*64
  float* acc_mid = (float*)(bits_low + 512 * 64);         // 512*81
  float* acc_low = acc_mid + 512 * 81;                    // 512*81
  float* ce = acc_low + 512 * 81;                         // 2

  hipLaunchKernelGGL(prep_kernel, dim3(512), dim3(192), 0, stream,
                     attn, fore, length, alpha, bits_mid, bits_low,
                     acc_mid, acc_low, ce);
  hipLaunchKernelGGL(main_kernel, dim3(5120), dim3(256), 0, stream,
                     cf_mid, cf_low, fore, out, bits_mid, bits_low,
                     acc_mid, acc_low, ce);
  hipLaunchKernelGGL(final_kernel, dim3(2), dim3(256), 0, stream,
                     acc_mid, acc_low, ce, length, out);
}